// Round 2
// baseline (533.458 us; speedup 1.0000x reference)
//
#include <hip/hip_runtime.h>
#include <stdint.h>
#include <stddef.h>

#define DEV __device__ __forceinline__

typedef __bf16 bf16_t;
typedef bf16_t bf16x8 __attribute__((ext_vector_type(8)));
typedef float f32x4 __attribute__((ext_vector_type(4)));
typedef unsigned short us4 __attribute__((ext_vector_type(4)));
typedef unsigned short us8 __attribute__((ext_vector_type(8)));

// ---------- bf16 <-> f32 helpers (bit-level, RNE) ----------
DEV float bf2f(unsigned short u) {
    union { unsigned int i; float f; } w; w.i = ((unsigned int)u) << 16; return w.f;
}
DEV unsigned short f2bf(float f) {
    union { unsigned int i; float f; } w; w.f = f;
    unsigned int u = w.i;
    return (unsigned short)((u + 0x7fffu + ((u >> 16) & 1u)) >> 16);
}

// ---------- async global -> LDS, 16B per lane ----------
DEV void gl_lds16(const void* g, void* l) {
    __builtin_amdgcn_global_load_lds((const __attribute__((address_space(1))) void*)g,
                                     (__attribute__((address_space(3))) void*)l,
                                     16, 0, 0);
}

// ======================================================================
// fp32 -> bf16 convert (4 elems/thread)
// ======================================================================
__global__ void __launch_bounds__(256)
cvt_f32_bf16(const float* __restrict__ src, unsigned short* __restrict__ dst) {
    int idx = (blockIdx.x * 256 + threadIdx.x) * 4;
    f32x4 v = *(const f32x4*)&src[idx];
    us4 o;
#pragma unroll
    for (int i = 0; i < 4; i++) o[i] = f2bf(v[i]);
    *(us4*)&dst[idx] = o;
}

// ======================================================================
// Weight transpose+convert: W fp32 (1024x1024 KxN) -> WT bf16 (NxK)
// ======================================================================
__global__ void __launch_bounds__(256)
transpose_w(const float* __restrict__ W0, const float* __restrict__ W1,
            const float* __restrict__ W2, const float* __restrict__ W3,
            unsigned short* __restrict__ T0, unsigned short* __restrict__ T1,
            unsigned short* __restrict__ T2, unsigned short* __restrict__ T3) {
    const float* W    = (blockIdx.z == 0) ? W0 : (blockIdx.z == 1) ? W1 : (blockIdx.z == 2) ? W2 : W3;
    unsigned short* T = (blockIdx.z == 0) ? T0 : (blockIdx.z == 1) ? T1 : (blockIdx.z == 2) ? T2 : T3;
    __shared__ float t[32][33];
    int tx = threadIdx.x, ty = threadIdx.y;       // 32 x 8
    int k0 = blockIdx.x * 32, n0 = blockIdx.y * 32;
#pragma unroll
    for (int r = 0; r < 4; r++)
        t[ty + r * 8][tx] = W[(size_t)(k0 + ty + r * 8) * 1024 + n0 + tx];
    __syncthreads();
#pragma unroll
    for (int r = 0; r < 4; r++)
        T[(size_t)(n0 + ty + r * 8) * 1024 + k0 + tx] = f2bf(t[tx][ty + r * 8]);
}

// ======================================================================
// GEMM C = A(4096x1024 bf16) @ Bt^T (bf16, N-major) + bias(fp32).
// 128x128 tile, BK=32, 4 waves each 64x64, mfma 16x16x32 bf16.
// MODE 0: bf16 split-head (B,H,S,D)        [Q, K]
// MODE 1: fp32 plain row-major (M,1024)    [final out]
// MODE 2: bf16 transposed split-head (B,H,D,S)  [V -> Vt]
// ======================================================================
template <int MODE>
__global__ void __launch_bounds__(256)
gemm_bt_128(const unsigned short* __restrict__ A,
            const unsigned short* __restrict__ Bt,
            const float* __restrict__ bias,
            void* __restrict__ CoutV) {
    const int K = 1024;
    __shared__ __align__(16) unsigned short As[128 * 32];
    __shared__ __align__(16) unsigned short Bs[128 * 32];
    int tid = threadIdx.x, lane = tid & 63, wid = tid >> 6;
    int mBase = blockIdx.x * 128, nBase = blockIdx.y * 128;
    int wm = (wid >> 1) * 64, wn = (wid & 1) * 64;
    int c0 = lane & 15, quad = lane >> 4;

    f32x4 acc[4][4] = {};

    for (int k0 = 0; k0 < K; k0 += 32) {
        __syncthreads();
#pragma unroll
        for (int i = 0; i < 2; i++) {
            int cb = wid * 64 + 256 * i;       // wave-uniform chunk base
            int cc = cb + lane;                // per-lane chunk
            int row = cc >> 2, kc = cc & 3;    // 4 x 16B chunks per 32-elem row
            gl_lds16(A  + (size_t)(mBase + row) * K + k0 + kc * 8, &As[cb * 8]);
            gl_lds16(Bt + (size_t)(nBase + row) * K + k0 + kc * 8, &Bs[cb * 8]);
        }
        __syncthreads();
        bf16x8 af[4], bfr[4];
#pragma unroll
        for (int t = 0; t < 4; t++) {
            af[t]  = *(const bf16x8*)&As[(wm + t * 16 + c0) * 32 + quad * 8];
            bfr[t] = *(const bf16x8*)&Bs[(wn + t * 16 + c0) * 32 + quad * 8];
        }
#pragma unroll
        for (int mt = 0; mt < 4; mt++)
#pragma unroll
            for (int nt = 0; nt < 4; nt++)
                acc[mt][nt] = __builtin_amdgcn_mfma_f32_16x16x32_bf16(af[mt], bfr[nt], acc[mt][nt], 0, 0, 0);
    }

    // Epilogue.  C/D layout: col = lane&15, row = quad*4 + reg  [m89 verified]
#pragma unroll
    for (int mt = 0; mt < 4; mt++) {
#pragma unroll
        for (int nt = 0; nt < 4; nt++) {
            int n = nBase + wn + nt * 16 + c0;
            float bv = bias[n];
            if (MODE == 2) {
                unsigned short* Cout = (unsigned short*)CoutV;
                // V transposed: (B,H,D,S); 4 consecutive rows (s) -> vector store
                int m0 = mBase + wm + mt * 16 + quad * 4;
                int b = m0 >> 10, s = m0 & 1023, h = n >> 6, d = n & 63;
                us4 pk;
#pragma unroll
                for (int r = 0; r < 4; r++) pk[r] = f2bf(acc[mt][nt][r] + bv);
                *(us4*)&Cout[((size_t)((b * 16 + h) * 64 + d)) * 1024 + s] = pk;
            } else {
#pragma unroll
                for (int r = 0; r < 4; r++) {
                    int m = mBase + wm + mt * 16 + quad * 4 + r;
                    float v = acc[mt][nt][r] + bv;
                    if (MODE == 0) {
                        unsigned short* Cout = (unsigned short*)CoutV;
                        int b = m >> 10, s = m & 1023, h = n >> 6, d = n & 63;
                        Cout[((size_t)((b * 16 + h) * 1024 + s)) * 64 + d] = f2bf(v);
                    } else {
                        float* Cout = (float*)CoutV;
                        Cout[(size_t)m * 1024 + n] = v;
                    }
                }
            }
        }
    }
}

// ======================================================================
// Fused QK^T / 64 + mask + softmax -> attn (fp32, to d_out attn region)
// One block = 16 q-rows of one (b,h).  Logits live in acc registers.
// ======================================================================
__global__ void __launch_bounds__(256)
attn_softmax(const unsigned short* __restrict__ Qws,
             const unsigned short* __restrict__ Kws,
             const float* __restrict__ maskp,
             float* __restrict__ attnOut) {
    __shared__ __align__(16) unsigned short Ks[256 * 64];  // 32KB
    __shared__ float redbuf[4][16];

    int tid = threadIdx.x, lane = tid & 63, wid = tid >> 6;
    int c0 = lane & 15, quad = lane >> 4;
    int bh = blockIdx.y, b = bh >> 4;
    int q0 = blockIdx.x * 16;

    // Q A-fragments (A[m=lane&15][k=quad*8+j])
    bf16x8 aq0, aq1;
    {
        const unsigned short* qp = Qws + ((size_t)bh * 1024 + q0 + c0) * 64 + quad * 8;
        aq0 = *(const bf16x8*)qp;
        aq1 = *(const bf16x8*)(qp + 32);
    }

    f32x4 acc[16] = {};

    for (int ch = 0; ch < 4; ch++) {
        __syncthreads();
#pragma unroll
        for (int i = 0; i < 8; i++) {
            int cb = wid * 64 + 256 * i;
            int cc = cb + lane;
            int row = cc >> 3, kc = cc & 7;   // 8 x 16B chunks per 64-elem row
            gl_lds16(Kws + ((size_t)bh * 1024 + ch * 256 + row) * 64 + kc * 8, &Ks[cb * 8]);
        }
        __syncthreads();
#pragma unroll
        for (int nt = 0; nt < 4; nt++) {
            int srow = wid * 64 + nt * 16 + c0;
            const unsigned short* kp = &Ks[srow * 64 + quad * 8];
            bf16x8 b0 = *(const bf16x8*)kp;
            bf16x8 b1 = *(const bf16x8*)(kp + 32);
            int ai = ch * 4 + nt;
            acc[ai] = __builtin_amdgcn_mfma_f32_16x16x32_bf16(aq0, b0, acc[ai], 0, 0, 0);
            acc[ai] = __builtin_amdgcn_mfma_f32_16x16x32_bf16(aq1, b1, acc[ai], 0, 0, 0);
        }
    }

    // scale 1/DEPTH, additive mask, row max
    float lmax[4] = {-3e38f, -3e38f, -3e38f, -3e38f};
#pragma unroll
    for (int i = 0; i < 16; i++) {
        int col = (i >> 2) * 256 + wid * 64 + (i & 3) * 16 + c0;
        float mval = maskp[b * 1024 + col] * (-1e9f);
#pragma unroll
        for (int r = 0; r < 4; r++) {
            float v = acc[i][r] * (1.0f / 64.0f) + mval;
            acc[i][r] = v;
            lmax[r] = fmaxf(lmax[r], v);
        }
    }
#pragma unroll
    for (int st = 1; st < 16; st <<= 1) {
#pragma unroll
        for (int r = 0; r < 4; r++) lmax[r] = fmaxf(lmax[r], __shfl_xor(lmax[r], st, 64));
    }
    if (c0 == 0) {
#pragma unroll
        for (int r = 0; r < 4; r++) redbuf[wid][quad * 4 + r] = lmax[r];
    }
    __syncthreads();
    float rmax[4];
#pragma unroll
    for (int r = 0; r < 4; r++) {
        int row = quad * 4 + r;
        rmax[r] = fmaxf(fmaxf(redbuf[0][row], redbuf[1][row]), fmaxf(redbuf[2][row], redbuf[3][row]));
    }
    float lsum[4] = {0.f, 0.f, 0.f, 0.f};
#pragma unroll
    for (int i = 0; i < 16; i++) {
#pragma unroll
        for (int r = 0; r < 4; r++) {
            float e = __expf(acc[i][r] - rmax[r]);
            acc[i][r] = e;
            lsum[r] += e;
        }
    }
#pragma unroll
    for (int st = 1; st < 16; st <<= 1) {
#pragma unroll
        for (int r = 0; r < 4; r++) lsum[r] += __shfl_xor(lsum[r], st, 64);
    }
    __syncthreads();   // all reads of redbuf(max) done before reuse
    if (c0 == 0) {
#pragma unroll
        for (int r = 0; r < 4; r++) redbuf[wid][quad * 4 + r] = lsum[r];
    }
    __syncthreads();
    float rinv[4];
#pragma unroll
    for (int r = 0; r < 4; r++) {
        int row = quad * 4 + r;
        rinv[r] = 1.0f / (redbuf[0][row] + redbuf[1][row] + redbuf[2][row] + redbuf[3][row]);
    }
    // store attn (fp32) to d_out attn region
    size_t base = ((size_t)bh * 1024 + q0) * 1024;
#pragma unroll
    for (int i = 0; i < 16; i++) {
        int col = (i >> 2) * 256 + wid * 64 + (i & 3) * 16 + c0;
#pragma unroll
        for (int r = 0; r < 4; r++) {
            int row = quad * 4 + r;
            attnOut[base + (size_t)row * 1024 + col] = acc[i][r] * rinv[r];
        }
    }
}

// ======================================================================
// ctx = attn @ V per head.  A = attn fp32 (1024x1024), Bt = Vt bf16 (64x1024).
// BM=128, N=64, BK=64.  A converted fp32->bf16 at fragment build.
// Writes ctx bf16 in (B,S,H*D).
// ======================================================================
__global__ void __launch_bounds__(256)
pv_gemm(const float* __restrict__ attn,
        const unsigned short* __restrict__ Vt,
        unsigned short* __restrict__ ctx) {
    __shared__ __align__(16) float Asf[128 * 64];          // 32KB
    __shared__ __align__(16) unsigned short Bs[64 * 64];   // 8KB
    int tid = threadIdx.x, lane = tid & 63, wid = tid >> 6;
    int c0 = lane & 15, quad = lane >> 4;
    int bh = blockIdx.y, b = bh >> 4, h = bh & 15;
    int mBase = blockIdx.x * 128;
    const float* Ab = attn + (size_t)bh * 1024 * 1024;
    const unsigned short* Bb = Vt + (size_t)bh * 64 * 1024;

    f32x4 acc[2][4] = {};

    for (int k0 = 0; k0 < 1024; k0 += 64) {
        __syncthreads();
#pragma unroll
        for (int i = 0; i < 8; i++) {  // A tile: 128x64 fp32 = 2048 x 16B chunks
            int cb = wid * 64 + 256 * i;
            int cc = cb + lane;
            int row = cc >> 4, kc = cc & 15;   // 16 chunks (4 floats each) per row
            gl_lds16(Ab + (size_t)(mBase + row) * 1024 + k0 + kc * 4, &Asf[cb * 4]);
        }
#pragma unroll
        for (int i = 0; i < 2; i++) {  // B tile: 64x64 bf16 = 512 x 16B chunks
            int cb = wid * 64 + 256 * i;
            int cc = cb + lane;
            int row = cc >> 3, kc = cc & 7;
            gl_lds16(Bb + (size_t)row * 1024 + k0 + kc * 8, &Bs[cb * 8]);
        }
        __syncthreads();
#pragma unroll
        for (int ks = 0; ks < 2; ks++) {
            bf16x8 af[2], bfr[4];
#pragma unroll
            for (int mt = 0; mt < 2; mt++) {
                const float* ap = &Asf[(wid * 32 + mt * 16 + c0) * 64 + ks * 32 + quad * 8];
                union { us8 u; bf16x8 b; } cv;
#pragma unroll
                for (int j = 0; j < 8; j++) cv.u[j] = f2bf(ap[j]);
                af[mt] = cv.b;
            }
#pragma unroll
            for (int nt = 0; nt < 4; nt++)
                bfr[nt] = *(const bf16x8*)&Bs[(nt * 16 + c0) * 64 + ks * 32 + quad * 8];
#pragma unroll
            for (int mt = 0; mt < 2; mt++)
#pragma unroll
                for (int nt = 0; nt < 4; nt++)
                    acc[mt][nt] = __builtin_amdgcn_mfma_f32_16x16x32_bf16(af[mt], bfr[nt], acc[mt][nt], 0, 0, 0);
        }
    }
#pragma unroll
    for (int mt = 0; mt < 2; mt++)
#pragma unroll
        for (int nt = 0; nt < 4; nt++)
#pragma unroll
            for (int r = 0; r < 4; r++) {
                int s = mBase + wid * 32 + mt * 16 + quad * 4 + r;
                int d = nt * 16 + c0;
                ctx[((size_t)(b * 1024 + s)) * 1024 + h * 64 + d] = f2bf(acc[mt][nt][r]);
            }
}

// ======================================================================
// host
// ======================================================================
extern "C" void kernel_launch(void* const* d_in, const int* in_sizes, int n_in,
                              void* d_out, int out_size, void* d_ws, size_t ws_size,
                              hipStream_t stream) {
    (void)in_sizes; (void)n_in; (void)out_size; (void)ws_size;
    const float* q    = (const float*)d_in[0];
    const float* k    = (const float*)d_in[1];
    const float* v    = (const float*)d_in[2];
    const float* mask = (const float*)d_in[3];
    const float* Wq   = (const float*)d_in[4];
    const float* bq   = (const float*)d_in[5];
    const float* Wk   = (const float*)d_in[6];
    const float* bk   = (const float*)d_in[7];
    const float* Wv   = (const float*)d_in[8];
    const float* bv   = (const float*)d_in[9];
    const float* Wo   = (const float*)d_in[10];
    const float* bo   = (const float*)d_in[11];

    float* outF  = (float*)d_out;                          // (B,S,1024): 4M floats
    float* attnF = outF + (size_t)4 * 1024 * 1024;         // (B,H,S,S): 64M floats

    unsigned short* wsu = (unsigned short*)d_ws;
    const size_t M1 = (size_t)1024 * 1024;
    unsigned short* WqT = wsu;                 // 1M u16 each
    unsigned short* WkT = wsu + 1 * M1;
    unsigned short* WvT = wsu + 2 * M1;
    unsigned short* WoT = wsu + 3 * M1;
    unsigned short* tmp = wsu + 4 * M1;        // bf16 copy of q/k/v (reused), 4M
    unsigned short* Qw  = wsu + 8 * M1;        // (B,H,S,D) 4M
    unsigned short* Kw  = wsu + 12 * M1;       // 4M
    unsigned short* Vtw = wsu + 16 * M1;       // (B,H,D,S) 4M
    unsigned short* ctx = wsu + 20 * M1;       // (B,S,1024) 4M  -> 48MB total

    transpose_w<<<dim3(32, 32, 4), dim3(32, 8), 0, stream>>>(Wq, Wk, Wv, Wo, WqT, WkT, WvT, WoT);

    cvt_f32_bf16<<<4096, 256, 0, stream>>>(q, tmp);
    gemm_bt_128<0><<<dim3(32, 8), 256, 0, stream>>>(tmp, WqT, bq, Qw);
    cvt_f32_bf16<<<4096, 256, 0, stream>>>(k, tmp);
    gemm_bt_128<0><<<dim3(32, 8), 256, 0, stream>>>(tmp, WkT, bk, Kw);
    cvt_f32_bf16<<<4096, 256, 0, stream>>>(v, tmp);
    gemm_bt_128<2><<<dim3(32, 8), 256, 0, stream>>>(tmp, WvT, bv, Vtw);

    attn_softmax<<<dim3(64, 64), 256, 0, stream>>>(Qw, Kw, mask, attnF);

    pv_gemm<<<dim3(8, 64), 256, 0, stream>>>(attnF, Vtw, ctx);

    gemm_bt_128<1><<<dim3(32, 8), 256, 0, stream>>>(ctx, WoT, bo, outF);
}

// Round 3
// 493.725 us; speedup vs baseline: 1.0805x; 1.0805x over previous
//
#include <hip/hip_runtime.h>
#include <stdint.h>
#include <stddef.h>

#define DEV __device__ __forceinline__

typedef __bf16 bf16_t;
typedef bf16_t bf16x8 __attribute__((ext_vector_type(8)));
typedef float f32x4 __attribute__((ext_vector_type(4)));
typedef unsigned short us4 __attribute__((ext_vector_type(4)));
typedef unsigned short us8 __attribute__((ext_vector_type(8)));

// ---------- bf16 <-> f32 helpers (bit-level, RNE) ----------
DEV float bf2f(unsigned short u) {
    union { unsigned int i; float f; } w; w.i = ((unsigned int)u) << 16; return w.f;
}
DEV unsigned short f2bf(float f) {
    union { unsigned int i; float f; } w; w.f = f;
    unsigned int u = w.i;
    return (unsigned short)((u + 0x7fffu + ((u >> 16) & 1u)) >> 16);
}

// ---------- async global -> LDS, 16B per lane ----------
DEV void gl_lds16(const void* g, void* l) {
    __builtin_amdgcn_global_load_lds((const __attribute__((address_space(1))) void*)g,
                                     (__attribute__((address_space(3))) void*)l,
                                     16, 0, 0);
}

// ======================================================================
// fp32 -> bf16 convert, 3 tensors in one dispatch (z selects)
// ======================================================================
__global__ void __launch_bounds__(256)
cvt3(const float* __restrict__ s0, const float* __restrict__ s1, const float* __restrict__ s2,
     unsigned short* __restrict__ d0, unsigned short* __restrict__ d1, unsigned short* __restrict__ d2) {
    const float* src    = (blockIdx.z == 0) ? s0 : (blockIdx.z == 1) ? s1 : s2;
    unsigned short* dst = (blockIdx.z == 0) ? d0 : (blockIdx.z == 1) ? d1 : d2;
    int idx = (blockIdx.x * 256 + threadIdx.x) * 4;
    f32x4 v = *(const f32x4*)&src[idx];
    us4 o;
#pragma unroll
    for (int i = 0; i < 4; i++) o[i] = f2bf(v[i]);
    *(us4*)&dst[idx] = o;
}

// ======================================================================
// Weight transpose+convert: W fp32 (1024x1024 KxN) -> WT bf16 (NxK)
// ======================================================================
__global__ void __launch_bounds__(256)
transpose_w(const float* __restrict__ W0, const float* __restrict__ W1,
            const float* __restrict__ W2, const float* __restrict__ W3,
            unsigned short* __restrict__ T0, unsigned short* __restrict__ T1,
            unsigned short* __restrict__ T2, unsigned short* __restrict__ T3) {
    const float* W    = (blockIdx.z == 0) ? W0 : (blockIdx.z == 1) ? W1 : (blockIdx.z == 2) ? W2 : W3;
    unsigned short* T = (blockIdx.z == 0) ? T0 : (blockIdx.z == 1) ? T1 : (blockIdx.z == 2) ? T2 : T3;
    __shared__ float t[32][33];
    int tx = threadIdx.x, ty = threadIdx.y;       // 32 x 8
    int k0 = blockIdx.x * 32, n0 = blockIdx.y * 32;
#pragma unroll
    for (int r = 0; r < 4; r++)
        t[ty + r * 8][tx] = W[(size_t)(k0 + ty + r * 8) * 1024 + n0 + tx];
    __syncthreads();
#pragma unroll
    for (int r = 0; r < 4; r++)
        T[(size_t)(n0 + ty + r * 8) * 1024 + k0 + tx] = f2bf(t[tx][ty + r * 8]);
}

// ======================================================================
// Fused Q/K/V projection: z picks (A, Bt, bias, out, mode).
// 128x128 tile, BK=32, 4 waves each 64x64, mfma 16x16x32 bf16.
// z=0,1: bf16 split-head (B,H,S,D);  z=2: bf16 (B,H,D,S) for V
// ======================================================================
__global__ void __launch_bounds__(256)
qkv_gemm(const unsigned short* __restrict__ Aq, const unsigned short* __restrict__ Ak,
         const unsigned short* __restrict__ Av,
         const unsigned short* __restrict__ BtQ, const unsigned short* __restrict__ BtK,
         const unsigned short* __restrict__ BtV,
         const float* __restrict__ biq, const float* __restrict__ bik,
         const float* __restrict__ biv,
         unsigned short* __restrict__ Qw, unsigned short* __restrict__ Kw,
         unsigned short* __restrict__ Vtw) {
    const int K = 1024;
    const unsigned short* A  = (blockIdx.z == 0) ? Aq  : (blockIdx.z == 1) ? Ak  : Av;
    const unsigned short* Bt = (blockIdx.z == 0) ? BtQ : (blockIdx.z == 1) ? BtK : BtV;
    const float* bias        = (blockIdx.z == 0) ? biq : (blockIdx.z == 1) ? bik : biv;
    unsigned short* Cout     = (blockIdx.z == 0) ? Qw  : (blockIdx.z == 1) ? Kw  : Vtw;
    const bool vmode = (blockIdx.z == 2);

    __shared__ __align__(16) unsigned short As[128 * 32];
    __shared__ __align__(16) unsigned short Bs[128 * 32];
    int tid = threadIdx.x, lane = tid & 63, wid = tid >> 6;
    int mBase = blockIdx.x * 128, nBase = blockIdx.y * 128;
    int wm = (wid >> 1) * 64, wn = (wid & 1) * 64;
    int c0 = lane & 15, quad = lane >> 4;

    f32x4 acc[4][4] = {};

    for (int k0 = 0; k0 < K; k0 += 32) {
        __syncthreads();
#pragma unroll
        for (int i = 0; i < 2; i++) {
            int cb = wid * 64 + 256 * i;
            int cc = cb + lane;
            int row = cc >> 2, kc = cc & 3;
            gl_lds16(A  + (size_t)(mBase + row) * K + k0 + kc * 8, &As[cb * 8]);
            gl_lds16(Bt + (size_t)(nBase + row) * K + k0 + kc * 8, &Bs[cb * 8]);
        }
        __syncthreads();
        bf16x8 af[4], bfr[4];
#pragma unroll
        for (int t = 0; t < 4; t++) {
            af[t]  = *(const bf16x8*)&As[(wm + t * 16 + c0) * 32 + quad * 8];
            bfr[t] = *(const bf16x8*)&Bs[(wn + t * 16 + c0) * 32 + quad * 8];
        }
#pragma unroll
        for (int mt = 0; mt < 4; mt++)
#pragma unroll
            for (int nt = 0; nt < 4; nt++)
                acc[mt][nt] = __builtin_amdgcn_mfma_f32_16x16x32_bf16(af[mt], bfr[nt], acc[mt][nt], 0, 0, 0);
    }

    // C/D layout: col = lane&15, row = quad*4 + reg
#pragma unroll
    for (int mt = 0; mt < 4; mt++) {
#pragma unroll
        for (int nt = 0; nt < 4; nt++) {
            int n = nBase + wn + nt * 16 + c0;
            float bv = bias[n];
            if (vmode) {
                int m0 = mBase + wm + mt * 16 + quad * 4;
                int b = m0 >> 10, s = m0 & 1023, h = n >> 6, d = n & 63;
                us4 pk;
#pragma unroll
                for (int r = 0; r < 4; r++) pk[r] = f2bf(acc[mt][nt][r] + bv);
                *(us4*)&Cout[((size_t)((b * 16 + h) * 64 + d)) * 1024 + s] = pk;
            } else {
#pragma unroll
                for (int r = 0; r < 4; r++) {
                    int m = mBase + wm + mt * 16 + quad * 4 + r;
                    int b = m >> 10, s = m & 1023, h = n >> 6, d = n & 63;
                    Cout[((size_t)((b * 16 + h) * 1024 + s)) * 64 + d] = f2bf(acc[mt][nt][r] + bv);
                }
            }
        }
    }
}

// ======================================================================
// Final projection: C = ctx @ WoT^T + bo -> fp32 (M,1024)
// ======================================================================
__global__ void __launch_bounds__(256)
out_gemm(const unsigned short* __restrict__ A,
         const unsigned short* __restrict__ Bt,
         const float* __restrict__ bias,
         float* __restrict__ Cout) {
    const int K = 1024;
    __shared__ __align__(16) unsigned short As[128 * 32];
    __shared__ __align__(16) unsigned short Bs[128 * 32];
    int tid = threadIdx.x, lane = tid & 63, wid = tid >> 6;
    int mBase = blockIdx.x * 128, nBase = blockIdx.y * 128;
    int wm = (wid >> 1) * 64, wn = (wid & 1) * 64;
    int c0 = lane & 15, quad = lane >> 4;

    f32x4 acc[4][4] = {};

    for (int k0 = 0; k0 < K; k0 += 32) {
        __syncthreads();
#pragma unroll
        for (int i = 0; i < 2; i++) {
            int cb = wid * 64 + 256 * i;
            int cc = cb + lane;
            int row = cc >> 2, kc = cc & 3;
            gl_lds16(A  + (size_t)(mBase + row) * K + k0 + kc * 8, &As[cb * 8]);
            gl_lds16(Bt + (size_t)(nBase + row) * K + k0 + kc * 8, &Bs[cb * 8]);
        }
        __syncthreads();
        bf16x8 af[4], bfr[4];
#pragma unroll
        for (int t = 0; t < 4; t++) {
            af[t]  = *(const bf16x8*)&As[(wm + t * 16 + c0) * 32 + quad * 8];
            bfr[t] = *(const bf16x8*)&Bs[(wn + t * 16 + c0) * 32 + quad * 8];
        }
#pragma unroll
        for (int mt = 0; mt < 4; mt++)
#pragma unroll
            for (int nt = 0; nt < 4; nt++)
                acc[mt][nt] = __builtin_amdgcn_mfma_f32_16x16x32_bf16(af[mt], bfr[nt], acc[mt][nt], 0, 0, 0);
    }
#pragma unroll
    for (int mt = 0; mt < 4; mt++)
#pragma unroll
        for (int nt = 0; nt < 4; nt++) {
            int n = nBase + wn + nt * 16 + c0;
            float bv = bias[n];
#pragma unroll
            for (int r = 0; r < 4; r++) {
                int m = mBase + wm + mt * 16 + quad * 4 + r;
                Cout[(size_t)m * 1024 + n] = acc[mt][nt][r] + bv;
            }
        }
}

// ======================================================================
// Fused QK^T/64 + mask + softmax + attn-write (fp32) + PV -> ctx (bf16)
// One block = 16 q-rows of one (b,h).  P kept on-chip (regs -> LDS).
//   Phase 1: QK^T, logits in regs (16 frags/wave, wave w owns cols
//            ch*256 + w*64 + nt*16 + c0)
//   Phase 2: softmax (shuffle + LDS reduce)
//   Phase 3: write attn fp32 to global; write P bf16 to LDS in A-layout
//            P_lds[wv][row][kk], kk = ch*64+nt*16+c0, stride 272,
//            chunk XOR-swizzle by (row>>2) for bank spread
//   Phase 4: PV: wave w computes ctx[0:16][w*16 : w*16+16] over all k;
//            Vs staged per 256-col quarter (Vt slice, 64 x 272)
// ======================================================================
__global__ void __launch_bounds__(256)
attn_pv(const unsigned short* __restrict__ Qws,
        const unsigned short* __restrict__ Kws,
        const unsigned short* __restrict__ Vtw,
        const float* __restrict__ maskp,
        float* __restrict__ attnOut,
        unsigned short* __restrict__ ctx) {
    __shared__ __align__(16) unsigned short ldsA[17408]; // Ks (256x64=16384) / P_lds (4*16*272)
    __shared__ __align__(16) unsigned short Vs[17408];   // 64 x 272
    __shared__ float redbuf[4][16];

    int tid = threadIdx.x, lane = tid & 63, wid = tid >> 6;
    int c0 = lane & 15, quad = lane >> 4;
    int bh = blockIdx.y, b = bh >> 4, h = bh & 15;
    int q0 = blockIdx.x * 16;

    // Q A-fragments
    bf16x8 aq0, aq1;
    {
        const unsigned short* qp = Qws + ((size_t)bh * 1024 + q0 + c0) * 64 + quad * 8;
        aq0 = *(const bf16x8*)qp;
        aq1 = *(const bf16x8*)(qp + 32);
    }

    f32x4 acc[16] = {};

    // ---- Phase 1: QK^T ----
    for (int ch = 0; ch < 4; ch++) {
        __syncthreads();
#pragma unroll
        for (int i = 0; i < 8; i++) {
            int cb = wid * 64 + 256 * i;
            int cc = cb + lane;
            int row = cc >> 3, kc = cc & 7;
            gl_lds16(Kws + ((size_t)bh * 1024 + ch * 256 + row) * 64 + kc * 8, &ldsA[cb * 8]);
        }
        __syncthreads();
#pragma unroll
        for (int nt = 0; nt < 4; nt++) {
            int srow = wid * 64 + nt * 16 + c0;
            const unsigned short* kp = &ldsA[srow * 64 + quad * 8];
            bf16x8 b0 = *(const bf16x8*)kp;
            bf16x8 b1 = *(const bf16x8*)(kp + 32);
            int ai = ch * 4 + nt;
            acc[ai] = __builtin_amdgcn_mfma_f32_16x16x32_bf16(aq0, b0, acc[ai], 0, 0, 0);
            acc[ai] = __builtin_amdgcn_mfma_f32_16x16x32_bf16(aq1, b1, acc[ai], 0, 0, 0);
        }
    }

    // ---- Phase 2: softmax ----
    float lmax[4] = {-3e38f, -3e38f, -3e38f, -3e38f};
#pragma unroll
    for (int i = 0; i < 16; i++) {
        int col = (i >> 2) * 256 + wid * 64 + (i & 3) * 16 + c0;
        float mval = maskp[b * 1024 + col] * (-1e9f);
#pragma unroll
        for (int r = 0; r < 4; r++) {
            float v = acc[i][r] * (1.0f / 64.0f) + mval;
            acc[i][r] = v;
            lmax[r] = fmaxf(lmax[r], v);
        }
    }
#pragma unroll
    for (int st = 1; st < 16; st <<= 1) {
#pragma unroll
        for (int r = 0; r < 4; r++) lmax[r] = fmaxf(lmax[r], __shfl_xor(lmax[r], st, 64));
    }
    if (c0 == 0) {
#pragma unroll
        for (int r = 0; r < 4; r++) redbuf[wid][quad * 4 + r] = lmax[r];
    }
    __syncthreads();   // also guarantees all QK^T MFMAs done reading ldsA
    float rmax[4];
#pragma unroll
    for (int r = 0; r < 4; r++) {
        int row = quad * 4 + r;
        rmax[r] = fmaxf(fmaxf(redbuf[0][row], redbuf[1][row]), fmaxf(redbuf[2][row], redbuf[3][row]));
    }
    float lsum[4] = {0.f, 0.f, 0.f, 0.f};
#pragma unroll
    for (int i = 0; i < 16; i++) {
#pragma unroll
        for (int r = 0; r < 4; r++) {
            float e = __expf(acc[i][r] - rmax[r]);
            acc[i][r] = e;
            lsum[r] += e;
        }
    }
#pragma unroll
    for (int st = 1; st < 16; st <<= 1) {
#pragma unroll
        for (int r = 0; r < 4; r++) lsum[r] += __shfl_xor(lsum[r], st, 64);
    }
    __syncthreads();
    if (c0 == 0) {
#pragma unroll
        for (int r = 0; r < 4; r++) redbuf[wid][quad * 4 + r] = lsum[r];
    }
    __syncthreads();
    float rinv[4];
#pragma unroll
    for (int r = 0; r < 4; r++) {
        int row = quad * 4 + r;
        rinv[r] = 1.0f / (redbuf[0][row] + redbuf[1][row] + redbuf[2][row] + redbuf[3][row]);
    }

    // ---- Phase 3: attn global write (fp32) + P -> LDS (bf16, A-layout) ----
    size_t gbase = ((size_t)bh * 1024 + q0) * 1024;
#pragma unroll
    for (int i = 0; i < 16; i++) {
        int kk = (i >> 2) * 64 + (i & 3) * 16 + c0;
        int col = (i >> 2) * 256 + wid * 64 + (i & 3) * 16 + c0;
        int kks = kk ^ (quad << 3);   // row>>2 == quad for all 4 regs
#pragma unroll
        for (int r = 0; r < 4; r++) {
            int row = quad * 4 + r;
            float pv = acc[i][r] * rinv[r];
            attnOut[gbase + (size_t)row * 1024 + col] = pv;
            ldsA[wid * 4352 + row * 272 + kks] = f2bf(pv);
        }
    }

    // ---- Phase 4: PV ----
    f32x4 ctxacc = {};
    for (int ch = 0; ch < 4; ch++) {
        __syncthreads();  // first iter: P writes done; later: prev MFMAs done with Vs
#pragma unroll
        for (int i = 0; i < 8; i++) {
            int cidx = tid + 256 * i;       // 2048 chunks of 8 elems (64 rows x 32)
            int drow = cidx >> 5;
            int soff = (cidx & 31) * 8;
            us8 val = *(const us8*)&Vtw[((size_t)(bh * 64 + drow)) * 1024 + ch * 256 + soff];
            *(us8*)&Vs[drow * 272 + soff] = val;
        }
        __syncthreads();
#pragma unroll
        for (int wv = 0; wv < 4; wv++) {
#pragma unroll
            for (int t = 0; t < 2; t++) {
                int kidx = (ch * 64 + t * 32 + quad * 8) ^ ((c0 >> 2) << 3);
                bf16x8 a  = *(const bf16x8*)&ldsA[wv * 4352 + c0 * 272 + kidx];
                bf16x8 bf_ = *(const bf16x8*)&Vs[(wid * 16 + c0) * 272 + wv * 64 + t * 32 + quad * 8];
                ctxacc = __builtin_amdgcn_mfma_f32_16x16x32_bf16(a, bf_, ctxacc, 0, 0, 0);
            }
        }
    }
    // ctx write: C-layout frag, rows=q, cols = wid*16+c0 (d)
#pragma unroll
    for (int r = 0; r < 4; r++) {
        int s = q0 + quad * 4 + r;
        ctx[((size_t)(b * 1024 + s)) * 1024 + h * 64 + wid * 16 + c0] = f2bf(ctxacc[r]);
    }
}

// ======================================================================
// host
// ======================================================================
extern "C" void kernel_launch(void* const* d_in, const int* in_sizes, int n_in,
                              void* d_out, int out_size, void* d_ws, size_t ws_size,
                              hipStream_t stream) {
    (void)in_sizes; (void)n_in; (void)out_size; (void)ws_size;
    const float* q    = (const float*)d_in[0];
    const float* k    = (const float*)d_in[1];
    const float* v    = (const float*)d_in[2];
    const float* mask = (const float*)d_in[3];
    const float* Wq   = (const float*)d_in[4];
    const float* bq   = (const float*)d_in[5];
    const float* Wk   = (const float*)d_in[6];
    const float* bk   = (const float*)d_in[7];
    const float* Wv   = (const float*)d_in[8];
    const float* bv   = (const float*)d_in[9];
    const float* Wo   = (const float*)d_in[10];
    const float* bo   = (const float*)d_in[11];

    float* outF  = (float*)d_out;                          // (B,S,1024): 4M floats
    float* attnF = outF + (size_t)4 * 1024 * 1024;         // (B,H,S,S): 64M floats

    unsigned short* wsu = (unsigned short*)d_ws;
    const size_t M1 = (size_t)1024 * 1024;
    unsigned short* WqT = wsu + 0 * M1;
    unsigned short* WkT = wsu + 1 * M1;
    unsigned short* WvT = wsu + 2 * M1;
    unsigned short* WoT = wsu + 3 * M1;
    unsigned short* tq  = wsu + 4 * M1;        // 4M each
    unsigned short* tk  = wsu + 8 * M1;
    unsigned short* tv  = wsu + 12 * M1;
    unsigned short* Qw  = wsu + 16 * M1;       // (B,H,S,D)
    unsigned short* Kw  = wsu + 20 * M1;
    unsigned short* Vtw = wsu + 24 * M1;       // (B,H,D,S)
    unsigned short* ctx = wsu + 28 * M1;       // (B,S,H*D)  -> 64MB total

    transpose_w<<<dim3(32, 32, 4), dim3(32, 8), 0, stream>>>(Wq, Wk, Wv, Wo, WqT, WkT, WvT, WoT);

    cvt3<<<dim3(4096, 1, 3), 256, 0, stream>>>(q, k, v, tq, tk, tv);

    qkv_gemm<<<dim3(32, 8, 3), 256, 0, stream>>>(tq, tk, tv, WqT, WkT, WvT, bq, bk, bv, Qw, Kw, Vtw);

    attn_pv<<<dim3(64, 64), 256, 0, stream>>>(Qw, Kw, Vtw, mask, attnF, ctx);

    out_gemm<<<dim3(32, 8), 256, 0, stream>>>(ctx, WoT, bo, outF);
}